// Round 1
// 419.414 us; speedup vs baseline: 1.0137x; 1.0137x over previous
//
#include <hip/hip_runtime.h>

typedef __attribute__((ext_vector_type(8))) short short8;
typedef __attribute__((ext_vector_type(4))) float floatx4;

__device__ __forceinline__ unsigned short f2bf(float f) {
    unsigned int x = __float_as_uint(f);
    x = x + 0x7FFFu + ((x >> 16) & 1u);   // RNE
    return (unsigned short)(x >> 16);
}

// ---------------------------------------------------------------------------
// MFMA 16x16 tile GEMM helper: C(M,N) = A(M,K) * B(N,K)^T + bscale*bias(N).
// A,B bf16 row-major K-contiguous. One wave per tile.
// A frag A[m=lane&15][k=q*8+j]; B frag B[n=lane&15][k=q*8+j];
// D: col=lane&15, row=q*4+r (learn_hip m89/m91). bias fp32.
// STATS: accumulate per-column (col&63) sum/sumsq partials into LDS.
// ---------------------------------------------------------------------------
template <typename OutT, bool STATS>
__device__ __forceinline__ void gemm_tile(
    const unsigned short* __restrict__ A, int lda,
    const unsigned short* __restrict__ B, int ldb,
    const float* __restrict__ bias, float bscale,
    OutT* __restrict__ C, int ldc, int tilesN, int K, int wave, int lane,
    float* sS, float* sSS)
{
    int tm = wave / tilesN, tn = wave % tilesN;
    int mn = lane & 15, q = lane >> 4;
    const short8* ap = (const short8*)(A + (size_t)(tm * 16 + mn) * lda + q * 8);
    const short8* bp = (const short8*)(B + (size_t)(tn * 16 + mn) * ldb + q * 8);
    floatx4 acc = {0.f, 0.f, 0.f, 0.f};
    #pragma unroll 4
    for (int k = 0; k < K; k += 32) {
        short8 a = *ap; ap += 4;
        short8 b = *bp; bp += 4;
        acc = __builtin_amdgcn_mfma_f32_16x16x32_bf16(a, b, acc, 0, 0, 0);
    }
    int col = tn * 16 + mn;
    float bv = bias[col] * bscale;
    float lsum = 0.f, lss = 0.f;
    #pragma unroll
    for (int r = 0; r < 4; ++r) {
        int row = tm * 16 + q * 4 + r;
        float v = acc[r] + bv;
        OutT* dst = C + (size_t)row * ldc + col;
        if constexpr (sizeof(OutT) == 2) *dst = (OutT)f2bf(v);
        else                             *dst = (OutT)v;
        if constexpr (STATS) { lsum += v; lss += v * v; }
    }
    if constexpr (STATS) {
        int d = col & 63;
        atomicAdd(&sS[d], lsum);
        atomicAdd(&sSS[d], lss);
    }
}

// ---------------------------------------------------------------------------
// K1 MEGA: all input-independent-order work in one launch.
//  blocks [0,1024):    ksum partials over n. k:(128,1024,512) f32 stream.
//  blocks [1024,3076): weights f32 -> bf16.
//  blocks [3076,5124): attn_out (output 0) = 1.0f.
//  blocks [5124,5128): BN1(x) -> xnbf bf16; block 5124 also zeroes stats.
// ---------------------------------------------------------------------------
__global__ __launch_bounds__(256) void k_mega(
    const float* __restrict__ kk, float* __restrict__ part,
    const float* __restrict__ Wx, const float* __restrict__ Wk,
    const float* __restrict__ Wo, const float* __restrict__ Wl,
    unsigned short* __restrict__ Wxbf, unsigned short* __restrict__ Wkbf,
    unsigned short* __restrict__ Wobf, unsigned short* __restrict__ Wlbf,
    float4* __restrict__ attn_out,
    const float* __restrict__ x, const float* __restrict__ g1,
    const float* __restrict__ b1, unsigned short* __restrict__ xnbf,
    float* __restrict__ stats)
{
    int blk = blockIdx.x, tid = threadIdx.x;
    if (blk < 1024) {
        int b = blk >> 3, c = blk & 7;
        int f4 = tid & 127;
        int rh = tid >> 7;
        const float4* base = (const float4*)kk
            + ((size_t)(b * 1024 + c * 128 + rh) * 128 + f4);
        float4 acc = {0.f, 0.f, 0.f, 0.f};
        #pragma unroll 8
        for (int it = 0; it < 64; ++it) {
            float4 v = base[(size_t)it * 256];
            acc.x += v.x; acc.y += v.y; acc.z += v.z; acc.w += v.w;
        }
        __shared__ float red[2][512];
        red[rh][f4 * 4 + 0] = acc.x;
        red[rh][f4 * 4 + 1] = acc.y;
        red[rh][f4 * 4 + 2] = acc.z;
        red[rh][f4 * 4 + 3] = acc.w;
        __syncthreads();
        for (int j = tid; j < 512; j += 256)
            part[((size_t)(c * 128 + b) << 9) + j] = red[0][j] + red[1][j];
    } else if (blk < 3076) {
        int f = (blk - 1024) * 256 + tid;   // float4 index, < 525312
        const float* src; unsigned short* dst; int off;
        if (f < 262144)      { src = Wx; dst = Wxbf; off = f; }
        else if (f < 393216) { src = Wk; dst = Wkbf; off = f - 262144; }
        else if (f < 524288) { src = Wo; dst = Wobf; off = f - 393216; }
        else                 { src = Wl; dst = Wlbf; off = f - 524288; }
        float4 v = ((const float4*)src)[off];
        uint2 o;
        o.x = (unsigned int)f2bf(v.x) | ((unsigned int)f2bf(v.y) << 16);
        o.y = (unsigned int)f2bf(v.z) | ((unsigned int)f2bf(v.w) << 16);
        *(uint2*)(dst + off * 4) = o;
    } else if (blk < 5124) {
        int idx = (blk - 3076) * 256 + tid;   // < 524288 float4
        float4 ones = {1.f, 1.f, 1.f, 1.f};
        attn_out[idx] = ones;
    } else {
        if (blk == 5124 && tid < 128) stats[tid] = 0.f;
        int c = (blk - 5124) * 256 + tid;
        float s = 0.f, ss = 0.f;
        #pragma unroll 8
        for (int b = 0; b < 128; ++b) {
            float v = x[b * 1024 + c];
            s += v; ss += v * v;
        }
        float m  = s * (1.f / 128.f);
        float va = ss * (1.f / 128.f) - m * m;
        float rs = rsqrtf(va + 1e-5f);
        float a  = rs * g1[c];
        float b2 = b1[c] - m * a;
        #pragma unroll 8
        for (int b = 0; b < 128; ++b)
            xnbf[b * 1024 + c] = f2bf(x[b * 1024 + c] * a + b2);
    }
}

// ---------------------------------------------------------------------------
// K2: blocks [0,64):   combine ksum partials -> ksumbf bf16 (128,512)
//     blocks [64,320): xq = xn @ Wx^T + bx (128,1024,K=1024) -> f32
//                      + fused BN2 partial stats (atomics into stats[128])
// (both consume only K1 outputs — no intra-kernel dependency)
// ---------------------------------------------------------------------------
__global__ __launch_bounds__(128) void k_combine_xq(
    const float* __restrict__ part, unsigned short* __restrict__ ksumbf,
    const unsigned short* __restrict__ xnbf, const unsigned short* __restrict__ Wxbf,
    const float* __restrict__ bx, float* __restrict__ xq,
    float* __restrict__ stats)
{
    int blk = blockIdx.x, tid = threadIdx.x;
    if (blk < 64) {
        int idx = blk * 128 + tid;   // 0..8191
        int b = idx >> 6;
        int j0 = (idx & 63) * 8;
        float s[8];
        #pragma unroll
        for (int u = 0; u < 8; ++u) s[u] = 0.f;
        #pragma unroll
        for (int c = 0; c < 8; ++c) {
            const float4* p = (const float4*)(part + ((size_t)(c * 128 + b) << 9) + j0);
            float4 a0 = p[0], a1 = p[1];
            s[0] += a0.x; s[1] += a0.y; s[2] += a0.z; s[3] += a0.w;
            s[4] += a1.x; s[5] += a1.y; s[6] += a1.z; s[7] += a1.w;
        }
        uint4 v;
        v.x = (unsigned int)f2bf(s[0]) | ((unsigned int)f2bf(s[1]) << 16);
        v.y = (unsigned int)f2bf(s[2]) | ((unsigned int)f2bf(s[3]) << 16);
        v.z = (unsigned int)f2bf(s[4]) | ((unsigned int)f2bf(s[5]) << 16);
        v.w = (unsigned int)f2bf(s[6]) | ((unsigned int)f2bf(s[7]) << 16);
        *(uint4*)(ksumbf + b * 512 + j0) = v;
    } else {
        __shared__ float sS[64], sSS[64];
        if (tid < 64) { sS[tid] = 0.f; sSS[tid] = 0.f; }
        __syncthreads();
        int wave = ((blk - 64) * 128 + tid) >> 6;
        gemm_tile<float, true>(xnbf, 1024, Wxbf, 1024, bx, 1.f, xq, 1024, 64, 1024,
                               wave, tid & 63, sS, sSS);
        __syncthreads();
        if (tid < 64)       atomicAdd(&stats[tid], sS[tid]);
        else                atomicAdd(&stats[tid], sSS[tid - 64]);
    }
}

// ---------------------------------------------------------------------------
// K3: blocks [0,256):   outf = ksum @ Wk^T + 1024*bk -> bf16 concat rows 0-127
//     blocks [256,512): latent = BN2(xq) @ Wlin^T + blin -> concat rows 128-255
//                       (BN2 stats finalized inline from stats[128], MFMA path)
// ---------------------------------------------------------------------------
__global__ __launch_bounds__(128) void k_outf_latent(
    const unsigned short* __restrict__ ksumbf, const unsigned short* __restrict__ Wkbf,
    const float* __restrict__ bk,
    const float* __restrict__ xq, const float* __restrict__ stats,
    const float* __restrict__ g2, const float* __restrict__ b2g,
    const unsigned short* __restrict__ Wlbf, const float* __restrict__ bl,
    unsigned short* __restrict__ concat)
{
    int blk = blockIdx.x, tid = threadIdx.x;
    if (blk < 256) {
        int wave = (blk * 128 + tid) >> 6;
        gemm_tile<unsigned short, false>(ksumbf, 512, Wkbf, 512, bk, 1024.f,
                                         concat, 1024, 64, 512, wave, tid & 63,
                                         nullptr, nullptr);
    } else {
        __shared__ float sa[64], sb[64];
        if (tid < 64) {
            float s = stats[tid], ss = stats[64 + tid];
            float m  = s * (1.f / 2048.f);
            float va = ss * (1.f / 2048.f) - m * m;
            float rs = rsqrtf(va + 1e-5f);
            float a  = rs * g2[tid];
            sa[tid] = a;
            sb[tid] = b2g[tid] - m * a;
        }
        __syncthreads();
        int w = tid >> 6, lane = tid & 63;
        int t = (blk - 256) * 2 + w;      // 0..511 = 128 row-tiles x 4 col-tiles
        int tm = t >> 2, tn = t & 3;      // row = tm*16+mn -> (b=tm, h=mn)
        int mn = lane & 15, q = lane >> 4;
        const float4* xp = (const float4*)(xq + (size_t)tm * 1024 + mn * 64 + q * 8);
        const short8* bp = (const short8*)(Wlbf + (tn * 16 + mn) * 64 + q * 8);
        floatx4 acc = {0.f, 0.f, 0.f, 0.f};
        #pragma unroll
        for (int kk = 0; kk < 2; ++kk) {
            float4 x0 = xp[0], x1 = xp[1];
            xp += 8;                       // +32 floats
            int kb = kk * 32 + q * 8;
            short8 af;
            af[0] = (short)f2bf(x0.x * sa[kb + 0] + sb[kb + 0]);
            af[1] = (short)f2bf(x0.y * sa[kb + 1] + sb[kb + 1]);
            af[2] = (short)f2bf(x0.z * sa[kb + 2] + sb[kb + 2]);
            af[3] = (short)f2bf(x0.w * sa[kb + 3] + sb[kb + 3]);
            af[4] = (short)f2bf(x1.x * sa[kb + 4] + sb[kb + 4]);
            af[5] = (short)f2bf(x1.y * sa[kb + 5] + sb[kb + 5]);
            af[6] = (short)f2bf(x1.z * sa[kb + 6] + sb[kb + 6]);
            af[7] = (short)f2bf(x1.w * sa[kb + 7] + sb[kb + 7]);
            short8 bf = *bp; bp += 4;      // +32 shorts
            acc = __builtin_amdgcn_mfma_f32_16x16x32_bf16(af, bf, acc, 0, 0, 0);
        }
        int d = tn * 16 + mn;
        float bv = bl[d];
        #pragma unroll
        for (int r = 0; r < 4; ++r) {
            int h = q * 4 + r;             // row = tm*16 + q*4 + r -> (b=tm, h)
            concat[(size_t)(128 + tm) * 1024 + h * 64 + d] = f2bf(acc[r] + bv);
        }
    }
}

// ---------------------------------------------------------------------------
// K4: final GEMM — [outf; xhid] (256,1024) @ Wo^T + bo -> outputs 1,2 (fp32)
// ---------------------------------------------------------------------------
__global__ __launch_bounds__(128) void k_final_gemm(
    const unsigned short* __restrict__ concat, const unsigned short* __restrict__ Wobf,
    const float* __restrict__ bo, float* __restrict__ out12)
{
    int wave = (blockIdx.x * 128 + threadIdx.x) >> 6;
    gemm_tile<float, false>(concat, 1024, Wobf, 1024, bo, 1.f, out12, 512, 32, 1024,
                            wave, threadIdx.x & 63, nullptr, nullptr);
}

// ---------------------------------------------------------------------------
// ws byte layout (ws_size >= 1 GiB per harness poison dispatches):
//   part    [0,       2097152)  f32 [8][128][512]
//   Wxbf    [2097152, 4194304)  bf16 (1024,1024)
//   Wkbf    [4194304, 5242880)  bf16 (1024,512)
//   Wobf    [5242880, 6291456)  bf16 (512,1024)
//   Wlbf    [6291456, 6299648)  bf16 (64,64)
//   xnbf    [6299648, 6561792)  bf16 (128,1024)
//   ksumbf  [6561792, 6692864)  bf16 (128,512)
//   xq      [6692864, 7217152)  f32  (128,1024)
//   stats   [7217152, 7217664)  f32  sum[64] | sumsq[64] (zeroed by K1)
//   concat  [7217664, 7741952)  bf16 (256,1024): rows 0-127 outf, 128-255 xhid
// d_out: [0, 2097152) floats = attn ones; then out2|out3 (256,512) fp32.
// Launch chain (4): mega -> {combine, xq+bn2stats} -> {outf, latent} -> final.
// ---------------------------------------------------------------------------
extern "C" void kernel_launch(void* const* d_in, const int* in_sizes, int n_in,
                              void* d_out, int out_size, void* d_ws, size_t ws_size,
                              hipStream_t stream) {
    (void)in_sizes; (void)n_in; (void)out_size; (void)ws_size;
    const float* x  = (const float*)d_in[0];
    const float* kk = (const float*)d_in[1];
    const float* g1 = (const float*)d_in[2];
    const float* b1 = (const float*)d_in[3];
    const float* Wx = (const float*)d_in[4];
    const float* bx = (const float*)d_in[5];
    const float* Wk = (const float*)d_in[6];
    const float* bk = (const float*)d_in[7];
    const float* g2 = (const float*)d_in[8];
    const float* b2 = (const float*)d_in[9];
    const float* Wl = (const float*)d_in[10];
    const float* bl = (const float*)d_in[11];
    const float* Wo = (const float*)d_in[12];
    const float* bo = (const float*)d_in[13];

    char* ws = (char*)d_ws;
    float*          part   = (float*)(ws + 0);
    unsigned short* Wxbf   = (unsigned short*)(ws + 2097152);
    unsigned short* Wkbf   = (unsigned short*)(ws + 4194304);
    unsigned short* Wobf   = (unsigned short*)(ws + 5242880);
    unsigned short* Wlbf   = (unsigned short*)(ws + 6291456);
    unsigned short* xnbf   = (unsigned short*)(ws + 6299648);
    unsigned short* ksumbf = (unsigned short*)(ws + 6561792);
    float*          xq     = (float*)(ws + 6692864);
    float*          stats  = (float*)(ws + 7217152);
    unsigned short* concat = (unsigned short*)(ws + 7217664);
    float*          out12  = (float*)d_out + 2097152;

    k_mega<<<5128, 256, 0, stream>>>(kk, part, Wx, Wk, Wo, Wl,
                                     Wxbf, Wkbf, Wobf, Wlbf,
                                     (float4*)d_out, x, g1, b1, xnbf, stats);
    k_combine_xq<<<320, 128, 0, stream>>>(part, ksumbf, xnbf, Wxbf, bx, xq, stats);
    k_outf_latent<<<512, 128, 0, stream>>>(ksumbf, Wkbf, bk, xq, stats,
                                           g2, b2, Wlbf, bl, concat);
    k_final_gemm<<<256, 128, 0, stream>>>(concat, Wobf, bo, out12);
}